// Round 1
// baseline (91.928 us; speedup 1.0000x reference)
//
#include <hip/hip_runtime.h>

#define NAG    8192
#define CHUNK  256
#define NCHUNK (NAG / CHUNK)   // 32 j-chunks
#define GG     36              // 6*6 bins
#define HID    128

// Kernel 1: per (agent-block, j-chunk) partial occupancy bitmask.
// partials[chunk][agent] : u64 with bits 0..35 = occupied relative cells.
__global__ __launch_bounds__(256) void occ_pair_masks(
    const float* __restrict__ obs, unsigned long long* __restrict__ partials) {
  const int t     = threadIdx.x;
  const int agent = blockIdx.x * 256 + t;   // 32 agent-blocks
  const int jbase = blockIdx.y * CHUNK;     // 32 chunks

  __shared__ float2 pj[CHUNK];              // pre-scaled (x*2, y*2) of chunk agents

  const float2* obs2 = (const float2*)obs;
  float2 p = obs2[jbase + t];
  pj[t] = make_float2(p.x * 2.0f, p.y * 2.0f);

  const float2 myp = obs2[agent];
  const float bx = 3.0f - myp.x * 2.0f;     // rel_x = obs_j.x*2 + bx
  const float by = 3.0f - myp.y * 2.0f;

  __syncthreads();

  unsigned long long mask = 0ull;
  #pragma unroll 8
  for (int jj = 0; jj < CHUNK; ++jj) {
    const float rx = pj[jj].x + bx;
    const float ry = pj[jj].y + by;
    // trunc == floor on the valid range [0,6); NaN fails the ordered >= 0 compare.
    const int ix = (int)rx;
    const int iy = (int)ry;
    const bool valid = (rx >= 0.0f) & (ry >= 0.0f) &
                       ((unsigned)ix < 6u) & ((unsigned)iy < 6u) &
                       ((jbase + jj) != agent);
    const int bitpos = valid ? (ix * 6 + iy) : 63;  // dump invalid into bit 63
    mask |= (1ull << bitpos);
  }
  partials[blockIdx.y * NAG + agent] = mask & ((1ull << GG) - 1ull);
}

// Kernel 2: OR-reduce partial masks, then out[i][:] = b + sum_{c set} W[c][:].
// Block = 256 threads = 8 agents x 32 lanes; each lane owns 4 consecutive cols.
__global__ __launch_bounds__(256) void occ_matmul(
    const unsigned long long* __restrict__ partials,
    const float* __restrict__ W, const float* __restrict__ b,
    float* __restrict__ out) {
  const int t     = threadIdx.x;
  const int lane  = t & 31;                 // column chunk (4 floats)
  const int agent = blockIdx.x * 8 + (t >> 5);

  // lane c of each 32-lane group loads partial for chunk c, OR-reduce within group
  unsigned long long m = partials[lane * NAG + agent];
  #pragma unroll
  for (int s = 16; s; s >>= 1) m |= __shfl_xor(m, s, 32);

  const unsigned mlo = (unsigned)m;
  const unsigned mhi = (unsigned)(m >> 32);

  const float4* W4 = (const float4*)W;      // 18 KB, L1/L2 resident
  float4 acc = ((const float4*)b)[lane];

  #pragma unroll
  for (int c = 0; c < GG; ++c) {
    const unsigned bit = (c < 32) ? ((mlo >> c) & 1u) : ((mhi >> (c - 32)) & 1u);
    const float sel = (float)bit;
    const float4 w = W4[c * 32 + lane];
    acc.x = fmaf(sel, w.x, acc.x);
    acc.y = fmaf(sel, w.y, acc.y);
    acc.z = fmaf(sel, w.z, acc.z);
    acc.w = fmaf(sel, w.w, acc.w);
  }
  ((float4*)out)[agent * 32 + lane] = acc;
}

extern "C" void kernel_launch(void* const* d_in, const int* in_sizes, int n_in,
                              void* d_out, int out_size, void* d_ws, size_t ws_size,
                              hipStream_t stream) {
  const float* obs = (const float*)d_in[0];   // [8192, 2] f32
  const float* W   = (const float*)d_in[1];   // [36, 128] f32
  const float* b   = (const float*)d_in[2];   // [128] f32
  float* out = (float*)d_out;                 // [8192, 128] f32
  unsigned long long* partials = (unsigned long long*)d_ws;  // 32*8192*8B = 2 MB

  occ_pair_masks<<<dim3(NAG / 256, NCHUNK), 256, 0, stream>>>(obs, partials);
  occ_matmul<<<dim3(NAG / 8), 256, 0, stream>>>(partials, W, b, out);
}